// Round 1
// baseline (529.850 us; speedup 1.0000x reference)
//
#include <hip/hip_runtime.h>
#include <stdint.h>
#include <math.h>

// InformerLayer on MI355X.
// Key algebraic fact: h[t,c] = x_t*mlp_w[c] + mlp_b[c]  (1x1 conv from ONE channel)
// => q/k/v are rank-1 + const in x_t; the whole ProbSparse attention reduces to
// scalar math on x plus per-head constants. Only the FFN is a real GEMM.
//
// B = b*N = 128 sequences, L = T = 256, C = 128, H = 8, E = 16, u = sample_k = 18.

#define EPSF 1e-5f

// ---------------------------------------------------------------------------
// threefry2x32 with key (0, 42) == jax.random.key(42)
// ---------------------------------------------------------------------------
__device__ __forceinline__ void threefry2x32_k42(uint32_t& x0, uint32_t& x1) {
  const uint32_t ks0 = 0u, ks1 = 42u, ks2 = 0u ^ 42u ^ 0x1BD11BDAu;
  x0 += ks0; x1 += ks1;
#define TF_R(d) { x0 += x1; x1 = (x1 << d) | (x1 >> (32 - d)); x1 ^= x0; }
  TF_R(13) TF_R(15) TF_R(26) TF_R(6)  x0 += ks1; x1 += ks2 + 1u;
  TF_R(17) TF_R(29) TF_R(16) TF_R(24) x0 += ks2; x1 += ks0 + 2u;
  TF_R(13) TF_R(15) TF_R(26) TF_R(6)  x0 += ks0; x1 += ks1 + 3u;
  TF_R(17) TF_R(29) TF_R(16) TF_R(24) x0 += ks1; x1 += ks2 + 4u;
  TF_R(13) TF_R(15) TF_R(26) TF_R(6)  x0 += ks2; x1 += ks0 + 5u;
#undef TF_R
}

__device__ __forceinline__ float waveSum(float v) {
  #pragma unroll
  for (int m = 32; m > 0; m >>= 1) v += __shfl_xor(v, m, 64);
  return v;
}

// ---------------------------------------------------------------------------
// Kernel A: idx (threefry) + folded constants.
// cst layout (floats): 0 Aq[128] |128 cq |256 Ak |384 ck |512 Av |640 cv |
//   768 alpha[8] |776 beta[8] |784 gamma[8] |792 delta[8] |
//   800 Wv[8][128] |1824 ccol[128]
// ---------------------------------------------------------------------------
__global__ __launch_bounds__(256) void setup_kernel(
    const float* __restrict__ mlp_w, const float* __restrict__ mlp_b,
    const float* __restrict__ wq, const float* __restrict__ bq,
    const float* __restrict__ wk, const float* __restrict__ bk,
    const float* __restrict__ wv, const float* __restrict__ bv,
    const float* __restrict__ wo, const float* __restrict__ bo,
    int* __restrict__ idxws, float* __restrict__ cst) {
  int tid = threadIdx.x;
  // idx[l][j] = bits[l*18+j] & 0xFF ; bits[i] = out0(pair i) for i<2304 else out1
  for (int p = tid; p < 2304; p += 256) {
    uint32_t a = (uint32_t)p, b = (uint32_t)(p + 2304);
    threefry2x32_k42(a, b);
    idxws[p]        = (int)(a & 0xFFu);
    idxws[p + 2304] = (int)(b & 0xFFu);
  }
  if (tid < 128) {
    float aq = 0.f, cq_ = 0.f, ak = 0.f, ck_ = 0.f, av = 0.f, cv_ = 0.f;
    for (int c = 0; c < 128; c++) {
      float w = mlp_w[c], bb = mlp_b[c];
      float q = wq[tid * 128 + c], k = wk[tid * 128 + c], v = wv[tid * 128 + c];
      aq += q * w; cq_ += q * bb;
      ak += k * w; ck_ += k * bb;
      av += v * w; cv_ += v * bb;
    }
    cst[0   + tid] = aq;
    cst[128 + tid] = cq_ + bq[tid];
    cst[256 + tid] = ak;
    cst[384 + tid] = ck_ + bk[tid];
    cst[512 + tid] = av;
    cst[640 + tid] = cv_ + bv[tid];
  }
  __syncthreads();
  if (tid < 8) {
    float a = 0.f, b = 0.f, g = 0.f, d = 0.f;
    for (int e = 0; e < 16; e++) {
      int j = tid * 16 + e;
      float Aq = cst[j], Cq = cst[128 + j], Ak = cst[256 + j], Ck = cst[384 + j];
      a += Aq * Ak; b += Aq * Ck; g += Cq * Ak; d += Cq * Ck;
    }
    cst[768 + tid] = a; cst[776 + tid] = b; cst[784 + tid] = g; cst[792 + tid] = d;
  }
  if (tid < 128) {
    float oc = 0.f;
    for (int h = 0; h < 8; h++) {
      float s = 0.f;
      for (int e = 0; e < 16; e++) {
        float w = wo[tid * 128 + h * 16 + e];
        s  += w * cst[512 + h * 16 + e];   // Av
        oc += w * cst[640 + h * 16 + e];   // cv
      }
      cst[800 + h * 128 + tid] = s;        // Wv[h][i]
    }
    cst[1824 + tid] = oc + bo[tid] + mlp_b[tid];  // ccol = mlp_b + oconst
  }
}

// ---------------------------------------------------------------------------
// Kernel B: per (seq, head): M measure -> top-18 -> softmax -> g coefficient.
// score(l,s) = alpha*x_l*x_s + beta*x_l + gamma*x_s + delta
// ---------------------------------------------------------------------------
__global__ __launch_bounds__(256) void attn_kernel(
    const float* __restrict__ x, const int* __restrict__ idx,
    const float* __restrict__ cst, float* __restrict__ g) {
  __shared__ float xr[256];
  __shared__ float M[256];
  __shared__ float redf[4];
  __shared__ float redf2[4];
  __shared__ int   redi[4];
  __shared__ int   mtop[18];
  int tid = threadIdx.x;
  int seq = blockIdx.x >> 3, h = blockIdx.x & 7;
  int wid = tid >> 6;
  float xv = x[seq * 256 + tid];
  xr[tid] = xv;
  float alpha = cst[768 + h], beta = cst[776 + h];
  float gamma = cst[784 + h], delta = cst[792 + h];
  // mean(x) over the sequence
  float s = waveSum(xv);
  if ((tid & 63) == 0) redf[wid] = s;
  __syncthreads();
  float meanx = (redf[0] + redf[1] + redf[2] + redf[3]) * (1.0f / 256.0f);
  // sparsity measure M[l] from 18 sampled keys
  float acoef = alpha * xv + gamma;   // multiplies x_s (l = tid is the query)
  float ccoef = beta  * xv + delta;
  float mx = -INFINITY, sm = 0.f;
  for (int j = 0; j < 18; j++) {
    float xs = xr[idx[tid * 18 + j]];
    float v = fmaf(acoef, xs, ccoef);
    mx = fmaxf(mx, v);
    sm += v;
  }
  M[tid] = mx - sm * (1.0f / 256.0f);
  __syncthreads();
  // top-18 extraction (lax.top_k tie-break: smaller index wins)
  for (int r = 0; r < 18; r++) {
    float v = M[tid]; int i = tid;
    #pragma unroll
    for (int m = 32; m > 0; m >>= 1) {
      float v2 = __shfl_xor(v, m, 64);
      int   i2 = __shfl_xor(i, m, 64);
      if (v2 > v || (v2 == v && i2 < i)) { v = v2; i = i2; }
    }
    if ((tid & 63) == 0) { redf[wid] = v; redi[wid] = i; }
    __syncthreads();
    if (tid == 0) {
      float bv = redf[0]; int bi = redi[0];
      for (int w = 1; w < 4; w++)
        if (redf[w] > bv || (redf[w] == bv && redi[w] < bi)) { bv = redf[w]; bi = redi[w]; }
      mtop[r] = bi;
      M[bi] = -INFINITY;
    }
    __syncthreads();
  }
  // default context coefficient = mean(x)
  g[(seq * 256 + tid) * 8 + h] = meanx;
  // 18 softmax rows -> overwrite g for selected queries
  for (int r = 0; r < 18; r++) {
    int l = mtop[r];
    float xl = xr[l];
    float ac = alpha * xl + gamma, cc = beta * xl + delta;
    float sc = 0.25f * fmaf(ac, xv, cc);   // / sqrt(E=16)
    float mxx = sc;
    #pragma unroll
    for (int m = 32; m > 0; m >>= 1) mxx = fmaxf(mxx, __shfl_xor(mxx, m, 64));
    if ((tid & 63) == 0) redf[wid] = mxx;
    __syncthreads();
    mxx = fmaxf(fmaxf(redf[0], redf[1]), fmaxf(redf[2], redf[3]));
    float p = expf(sc - mxx);
    float ps = p, pw = p * xv;
    #pragma unroll
    for (int m = 32; m > 0; m >>= 1) {
      ps += __shfl_xor(ps, m, 64);
      pw += __shfl_xor(pw, m, 64);
    }
    __syncthreads();   // redf reads above must finish before rewrite
    if ((tid & 63) == 0) { redf[wid] = ps; redf2[wid] = pw; }
    __syncthreads();
    if (tid == 0) {
      float S = redf[0] + redf[1] + redf[2] + redf[3];
      float W = redf2[0] + redf2[1] + redf2[2] + redf2[3];
      g[(seq * 256 + l) * 8 + h] = W / S;
    }
    __syncthreads();
  }
}

// ---------------------------------------------------------------------------
// Kernel C: one block per (b, t). 32 tokens (n=0..31) share (b,t):
//   r = x_t*mlp_w + ccol + sum_h g_h*Wv[h];  x1 = LN1(r)
//   FFN 128->512->128 (fp32, register-tiled through LDS), LN2,
//   and the sum over N=32 is done locally -> one store per output element.
// ---------------------------------------------------------------------------
#define DOT4(p, q) ((p).x*(q).x + (p).y*(q).y + (p).z*(q).z + (p).w*(q).w)

__global__ __launch_bounds__(256) void ffn_kernel(
    const float* __restrict__ x, const float* __restrict__ g,
    const float* __restrict__ cst, const float* __restrict__ mlp_w,
    const float* __restrict__ w1, const float* __restrict__ b1,
    const float* __restrict__ w2, const float* __restrict__ b2,
    const float* __restrict__ ln1g, const float* __restrict__ ln1b,
    const float* __restrict__ ln2g, const float* __restrict__ ln2b,
    float* __restrict__ out) {
  __shared__ float x1n[32][128];   // [n][c] 16 KB
  __shared__ float a1n[32][256];   // [n][f-chunk] 32 KB (reused for out2 at end)
  __shared__ float red[8];
  int tid = threadIdx.x;
  int b = blockIdx.x >> 8, t = blockIdx.x & 255;
  const float* Wv   = cst + 800;
  const float* ccol = cst + 1824;

  // ---- phase 1: r -> LN1 -> x1, two tokens at a time (128 threads each) ----
  {
    int c = tid & 127, half = tid >> 7, wid = tid >> 6;
    float mw = mlp_w[c], cc0 = ccol[c];
    float wv8[8];
    #pragma unroll
    for (int hh = 0; hh < 8; hh++) wv8[hh] = Wv[hh * 128 + c];
    float g1 = ln1g[c], bb1 = ln1b[c];
    for (int np = 0; np < 16; np++) {
      int n = np * 2 + half;
      int seq = b * 32 + n;
      float xval = x[seq * 256 + t];
      const float* gp = g + (size_t)(seq * 256 + t) * 8;
      float r = fmaf(xval, mw, cc0);
      #pragma unroll
      for (int hh = 0; hh < 8; hh++) r = fmaf(gp[hh], wv8[hh], r);
      float su = waveSum(r);
      if ((tid & 63) == 0) red[wid] = su;
      __syncthreads();
      float mu = (red[half * 2] + red[half * 2 + 1]) * (1.0f / 128.0f);
      float d = r - mu;
      float vs = waveSum(d * d);
      if ((tid & 63) == 0) red[4 + wid] = vs;
      __syncthreads();
      float var = (red[4 + half * 2] + red[4 + half * 2 + 1]) * (1.0f / 128.0f);
      x1n[n][c] = d * rsqrtf(var + EPSF) * g1 + bb1;
      __syncthreads();
    }
  }

  // ---- phase 2: FFN, f in 2 chunks of 256 ----
  // GEMM1 mapping: fh=tid&63 owns f=fh*4..+3, nh=tid>>6 owns n=nh*8..+7
  // GEMM2 mapping: cq=tid&31 owns c=cq*4..+3, ng=tid>>5 owns n=ng*4..+3
  float yacc[4][4];
  #pragma unroll
  for (int i = 0; i < 4; i++)
    #pragma unroll
    for (int j = 0; j < 4; j++) yacc[i][j] = 0.f;
  int cq = tid & 31, ng = tid >> 5;
  int fh = tid & 63, nh = tid >> 6;

  for (int fc = 0; fc < 2; fc++) {
    float acc[4][8];
    #pragma unroll
    for (int k = 0; k < 4; k++)
      #pragma unroll
      for (int j = 0; j < 8; j++) acc[k][j] = 0.f;
    const float* w1r = w1 + (size_t)(fc * 256 + fh * 4) * 128;
    for (int c4 = 0; c4 < 128; c4 += 4) {
      float4 wr0 = *(const float4*)(w1r + 0 * 128 + c4);
      float4 wr1 = *(const float4*)(w1r + 1 * 128 + c4);
      float4 wr2 = *(const float4*)(w1r + 2 * 128 + c4);
      float4 wr3 = *(const float4*)(w1r + 3 * 128 + c4);
      #pragma unroll
      for (int j = 0; j < 8; j++) {
        float4 xv = *(const float4*)&x1n[nh * 8 + j][c4];  // wave-broadcast
        acc[0][j] += DOT4(wr0, xv);
        acc[1][j] += DOT4(wr1, xv);
        acc[2][j] += DOT4(wr2, xv);
        acc[3][j] += DOT4(wr3, xv);
      }
    }
    __syncthreads();  // previous chunk's GEMM2 reads of a1n must be done
    float4 b1v = *(const float4*)(b1 + fc * 256 + fh * 4);
    #pragma unroll
    for (int j = 0; j < 8; j++) {
      float4 o;
      o.x = fmaxf(acc[0][j] + b1v.x, 0.f);
      o.y = fmaxf(acc[1][j] + b1v.y, 0.f);
      o.z = fmaxf(acc[2][j] + b1v.z, 0.f);
      o.w = fmaxf(acc[3][j] + b1v.w, 0.f);
      *(float4*)&a1n[nh * 8 + j][fh * 4] = o;   // contiguous, conflict-free
    }
    __syncthreads();
    const float* w2r = w2 + (size_t)(cq * 4) * 512 + fc * 256;
    for (int f4 = 0; f4 < 256; f4 += 4) {
      float4 u0 = *(const float4*)(w2r + 0 * 512 + f4);
      float4 u1 = *(const float4*)(w2r + 1 * 512 + f4);
      float4 u2 = *(const float4*)(w2r + 2 * 512 + f4);
      float4 u3 = *(const float4*)(w2r + 3 * 512 + f4);
      float4 a0 = *(const float4*)&a1n[ng * 4 + 0][f4];
      float4 a1v = *(const float4*)&a1n[ng * 4 + 1][f4];
      float4 a2 = *(const float4*)&a1n[ng * 4 + 2][f4];
      float4 a3 = *(const float4*)&a1n[ng * 4 + 3][f4];
      yacc[0][0] += DOT4(u0, a0);  yacc[0][1] += DOT4(u0, a1v);
      yacc[0][2] += DOT4(u0, a2);  yacc[0][3] += DOT4(u0, a3);
      yacc[1][0] += DOT4(u1, a0);  yacc[1][1] += DOT4(u1, a1v);
      yacc[1][2] += DOT4(u1, a2);  yacc[1][3] += DOT4(u1, a3);
      yacc[2][0] += DOT4(u2, a0);  yacc[2][1] += DOT4(u2, a1v);
      yacc[2][2] += DOT4(u2, a2);  yacc[2][3] += DOT4(u2, a3);
      yacc[3][0] += DOT4(u3, a0);  yacc[3][1] += DOT4(u3, a1v);
      yacc[3][2] += DOT4(u3, a2);  yacc[3][3] += DOT4(u3, a3);
    }
    __syncthreads();
  }

  // ---- phase 3: +b2, residual, LN2, local sum over the 32 tokens ----
  int cbase = cq * 4;
  float4 b2v  = *(const float4*)(b2 + cbase);
  float4 g2v  = *(const float4*)(ln2g + cbase);
  float4 bb2v = *(const float4*)(ln2b + cbase);
  float o2[4][4];
  #pragma unroll
  for (int jj = 0; jj < 4; jj++) {
    int n = ng * 4 + jj;
    float4 x1v = *(const float4*)&x1n[n][cbase];
    float z0 = x1v.x + yacc[0][jj] + b2v.x;
    float z1 = x1v.y + yacc[1][jj] + b2v.y;
    float z2 = x1v.z + yacc[2][jj] + b2v.z;
    float z3 = x1v.w + yacc[3][jj] + b2v.w;
    float su = z0 + z1 + z2 + z3;
    #pragma unroll
    for (int m = 1; m <= 16; m <<= 1) su += __shfl_xor(su, m, 64);  // 32-lane group
    float mu = su * (1.0f / 128.0f);
    z0 -= mu; z1 -= mu; z2 -= mu; z3 -= mu;
    float q = z0 * z0 + z1 * z1 + z2 * z2 + z3 * z3;
    #pragma unroll
    for (int m = 1; m <= 16; m <<= 1) q += __shfl_xor(q, m, 64);
    float inv = rsqrtf(q * (1.0f / 128.0f) + EPSF);
    o2[0][jj] = z0 * inv * g2v.x + bb2v.x;
    o2[1][jj] = z1 * inv * g2v.y + bb2v.y;
    o2[2][jj] = z2 * inv * g2v.z + bb2v.z;
    o2[3][jj] = z3 * inv * g2v.w + bb2v.w;
  }
  __syncthreads();   // everyone done reading a1n as activations
  #pragma unroll
  for (int jj = 0; jj < 4; jj++) {
    *(float4*)&a1n[ng * 4 + jj][cbase] =
        make_float4(o2[0][jj], o2[1][jj], o2[2][jj], o2[3][jj]);
  }
  __syncthreads();
  if (tid < 128) {
    float su = 0.f;
    #pragma unroll
    for (int n = 0; n < 32; n++) su += a1n[n][tid];
    out[(size_t)(b * 128 + tid) * 256 + t] = su;   // out[b][c][t]
  }
}

// ---------------------------------------------------------------------------
extern "C" void kernel_launch(void* const* d_in, const int* in_sizes, int n_in,
                              void* d_out, int out_size, void* d_ws, size_t ws_size,
                              hipStream_t stream) {
  (void)in_sizes; (void)n_in; (void)out_size; (void)ws_size;
  const float* x    = (const float*)d_in[0];
  const float* mlpw = (const float*)d_in[1];
  const float* mlpb = (const float*)d_in[2];
  const float* wq   = (const float*)d_in[3];
  const float* bq   = (const float*)d_in[4];
  const float* wk   = (const float*)d_in[5];
  const float* bk   = (const float*)d_in[6];
  const float* wv   = (const float*)d_in[7];
  const float* bv   = (const float*)d_in[8];
  const float* wo   = (const float*)d_in[9];
  const float* bo   = (const float*)d_in[10];
  const float* w1   = (const float*)d_in[11];
  const float* b1   = (const float*)d_in[12];
  const float* w2   = (const float*)d_in[13];
  const float* b2   = (const float*)d_in[14];
  const float* ln1g = (const float*)d_in[15];
  const float* ln1b = (const float*)d_in[16];
  const float* ln2g = (const float*)d_in[17];
  const float* ln2b = (const float*)d_in[18];

  char* ws = (char*)d_ws;
  int*   idxws = (int*)(ws);               // 4608 ints
  float* cst   = (float*)(ws + 32768);     // 1952 floats
  float* gbuf  = (float*)(ws + 65536);     // 128*256*8 floats = 1 MB
  float* outp  = (float*)d_out;

  hipLaunchKernelGGL(setup_kernel, dim3(1), dim3(256), 0, stream,
                     mlpw, mlpb, wq, bq, wk, bk, wv, bv, wo, bo, idxws, cst);
  hipLaunchKernelGGL(attn_kernel, dim3(1024), dim3(256), 0, stream,
                     x, idxws, cst, gbuf);
  hipLaunchKernelGGL(ffn_kernel, dim3(1024), dim3(256), 0, stream,
                     x, gbuf, cst, mlpw, w1, b1, w2, b2,
                     ln1g, ln1b, ln2g, ln2b, outp);
}

// Round 2
// 178.463 us; speedup vs baseline: 2.9690x; 2.9690x over previous
//
#include <hip/hip_runtime.h>
#include <stdint.h>
#include <math.h>

// InformerLayer on MI355X — round 2.
// h[t,c] = x_t*mlp_w[c] + mlp_b[c]  => attention collapses to scalar math on x;
// FFN is the only real GEMM -> bf16 MFMA (16x16x32), fully fused mega-kernel.
// B = 128 seqs, L = 256, C = 128, H = 8, E = 16, u = sample_k = 18.

#define EPSF 1e-5f

typedef short bf16x8 __attribute__((ext_vector_type(8)));
typedef float f32x4  __attribute__((ext_vector_type(4)));

__device__ __forceinline__ unsigned short f2bf(float f) {
  union { float f; unsigned u; } v; v.f = f;
  unsigned r = v.u + 0x7FFFu + ((v.u >> 16) & 1u);
  return (unsigned short)(r >> 16);
}
__device__ __forceinline__ float bf2f(unsigned short u) {
  union { unsigned u; float f; } v; v.u = ((unsigned)u) << 16;
  return v.f;
}
__device__ __forceinline__ float waveSum(float v) {
  #pragma unroll
  for (int m = 32; m > 0; m >>= 1) v += __shfl_xor(v, m);
  return v;
}

// ---------------------------------------------------------------------------
// threefry2x32 with key (0, 42) == jax.random.key(42)
// ---------------------------------------------------------------------------
__device__ __forceinline__ void threefry2x32_k42(uint32_t& x0, uint32_t& x1) {
  const uint32_t ks0 = 0u, ks1 = 42u, ks2 = 0u ^ 42u ^ 0x1BD11BDAu;
  x0 += ks0; x1 += ks1;
#define TF_R(d) { x0 += x1; x1 = (x1 << d) | (x1 >> (32 - d)); x1 ^= x0; }
  TF_R(13) TF_R(15) TF_R(26) TF_R(6)  x0 += ks1; x1 += ks2 + 1u;
  TF_R(17) TF_R(29) TF_R(16) TF_R(24) x0 += ks2; x1 += ks0 + 2u;
  TF_R(13) TF_R(15) TF_R(26) TF_R(6)  x0 += ks0; x1 += ks1 + 3u;
  TF_R(17) TF_R(29) TF_R(16) TF_R(24) x0 += ks1; x1 += ks2 + 4u;
  TF_R(13) TF_R(15) TF_R(26) TF_R(6)  x0 += ks2; x1 += ks0 + 5u;
#undef TF_R
}

// ---------------------------------------------------------------------------
// Kernel A (grid 32): block 0: idxT (transposed) + folded constants;
// all blocks: w1/w2 -> bf16.
// cst layout (floats): 0 Aq[128] |128 cq |256 Ak |384 ck |512 Av |640 cv |
//   768 alpha[8] |776 beta[8] |784 gamma[8] |792 delta[8] |
//   800 Wv[8][128] |1824 ccol[128]
// ---------------------------------------------------------------------------
__global__ __launch_bounds__(256) void setup_kernel(
    const float* __restrict__ mlp_w, const float* __restrict__ mlp_b,
    const float* __restrict__ wq, const float* __restrict__ bq,
    const float* __restrict__ wk, const float* __restrict__ bk,
    const float* __restrict__ wv, const float* __restrict__ bv,
    const float* __restrict__ wo, const float* __restrict__ bo,
    const float* __restrict__ w1, const float* __restrict__ w2,
    int* __restrict__ idxT, float* __restrict__ cst,
    unsigned short* __restrict__ w1bf, unsigned short* __restrict__ w2bf) {
  int tid = threadIdx.x;
  // ---- all blocks: weight conversion ----
  {
    int gid = blockIdx.x * 256 + tid;        // 0..8191, 16 elems each
    int base = gid * 16;
    const float* src; unsigned short* dst; int off;
    if (base < 65536) { src = w1; dst = w1bf; off = base; }
    else              { src = w2; dst = w2bf; off = base - 65536; }
    #pragma unroll 4
    for (int k = 0; k < 16; k++) dst[off + k] = f2bf(src[off + k]);
  }
  if (blockIdx.x != 0) return;
  // ---- idx, transposed: idxT[j][l] ----
  for (int p = tid; p < 2304; p += 256) {
    uint32_t a = (uint32_t)p, bb = (uint32_t)(p + 2304);
    threefry2x32_k42(a, bb);
    int l0 = p / 18, j0 = p - l0 * 18;
    int p2 = p + 2304;
    int l1 = p2 / 18, j1 = p2 - l1 * 18;
    idxT[j0 * 256 + l0] = (int)(a & 0xFFu);
    idxT[j1 * 256 + l1] = (int)(bb & 0xFFu);
  }
  if (tid < 128) {
    float aq = 0.f, cq_ = 0.f, ak = 0.f, ck_ = 0.f, av = 0.f, cv_ = 0.f;
    for (int c = 0; c < 128; c++) {
      float w = mlp_w[c], bb = mlp_b[c];
      float q = wq[tid * 128 + c], k = wk[tid * 128 + c], v = wv[tid * 128 + c];
      aq += q * w; cq_ += q * bb;
      ak += k * w; ck_ += k * bb;
      av += v * w; cv_ += v * bb;
    }
    cst[0   + tid] = aq;
    cst[128 + tid] = cq_ + bq[tid];
    cst[256 + tid] = ak;
    cst[384 + tid] = ck_ + bk[tid];
    cst[512 + tid] = av;
    cst[640 + tid] = cv_ + bv[tid];
  }
  __syncthreads();
  if (tid < 8) {
    float a = 0.f, b = 0.f, g = 0.f, d = 0.f;
    for (int e = 0; e < 16; e++) {
      int j = tid * 16 + e;
      float Aq = cst[j], Cq = cst[128 + j], Ak = cst[256 + j], Ck = cst[384 + j];
      a += Aq * Ak; b += Aq * Ck; g += Cq * Ak; d += Cq * Ck;
    }
    cst[768 + tid] = a; cst[776 + tid] = b; cst[784 + tid] = g; cst[792 + tid] = d;
  }
  if (tid < 128) {
    float oc = 0.f;
    for (int h = 0; h < 8; h++) {
      float s = 0.f;
      for (int e = 0; e < 16; e++) {
        float w = wo[tid * 128 + h * 16 + e];
        s  += w * cst[512 + h * 16 + e];   // Av
        oc += w * cst[640 + h * 16 + e];   // cv
      }
      cst[800 + h * 128 + tid] = s;        // Wv[h][i]
    }
    cst[1824 + tid] = oc + bo[tid] + mlp_b[tid];  // ccol
  }
}

// ---------------------------------------------------------------------------
// Kernel B: per (seq, head-pair). score(l,s) = a*x_l*x_s + b*x_l + g*x_s + d.
// Sample stats (max/min/sum over the 18 sampled keys) are head-independent.
// Softmax row: g = sum_s x_s e^{w x_s} / sum_s e^{w x_s}, w = 0.25*(alpha x_l + gamma).
// Top-18 via rank counting (tie-break: smaller index, matches lax.top_k).
// ---------------------------------------------------------------------------
__global__ __launch_bounds__(256) void attn_kernel(
    const float* __restrict__ x, const int* __restrict__ idxT,
    const float* __restrict__ cst, float* __restrict__ g) {
  __shared__ float xr[256];
  __shared__ float Mb[512];     // [hl][l]
  __shared__ float selv[512];   // [hl][l]
  __shared__ float rsum[4], rmax[4], rmin[4];
  __shared__ int   items[64];
  __shared__ float witem[64];
  __shared__ int   cnt;
  int tid = threadIdx.x, lane = tid & 63, w = tid >> 6;
  int seq = blockIdx.x >> 2, hg = blockIdx.x & 3;
  if (tid == 0) cnt = 0;
  float xv = x[seq * 256 + tid];
  xr[tid] = xv;
  float s = waveSum(xv);
  float mx = xv, mn = xv;
  #pragma unroll
  for (int m = 32; m > 0; m >>= 1) {
    mx = fmaxf(mx, __shfl_xor(mx, m));
    mn = fminf(mn, __shfl_xor(mn, m));
  }
  if (lane == 0) { rsum[w] = s; rmax[w] = mx; rmin[w] = mn; }
  __syncthreads();
  float meanx = (rsum[0] + rsum[1] + rsum[2] + rsum[3]) * (1.0f / 256.0f);
  float maxx = fmaxf(fmaxf(rmax[0], rmax[1]), fmaxf(rmax[2], rmax[3]));
  float minx = fminf(fminf(rmin[0], rmin[1]), fminf(rmin[2], rmin[3]));
  // head-independent sample stats for query l = tid
  float mx18 = -INFINITY, mn18 = INFINITY, s18 = 0.f;
  #pragma unroll 3
  for (int j = 0; j < 18; j++) {
    float xs = xr[idxT[j * 256 + tid]];
    mx18 = fmaxf(mx18, xs); mn18 = fminf(mn18, xs); s18 += xs;
  }
  int h0 = hg * 2, h1 = h0 + 1;
  float al0 = cst[768 + h0], be0 = cst[776 + h0], ga0 = cst[784 + h0], de0 = cst[792 + h0];
  float al1 = cst[768 + h1], be1 = cst[776 + h1], ga1 = cst[784 + h1], de1 = cst[792 + h1];
  float ac0 = fmaf(al0, xv, ga0), cc0 = fmaf(be0, xv, de0);
  float ac1 = fmaf(al1, xv, ga1), cc1 = fmaf(be1, xv, de1);
  float M0 = ((ac0 >= 0.f ? ac0 * mx18 : ac0 * mn18) + cc0)
           - (fmaf(ac0, s18, 18.f * cc0)) * (1.0f / 256.0f);
  float M1 = ((ac1 >= 0.f ? ac1 * mx18 : ac1 * mn18) + cc1)
           - (fmaf(ac1, s18, 18.f * cc1)) * (1.0f / 256.0f);
  Mb[tid] = M0; Mb[256 + tid] = M1;
  __syncthreads();
  int r0 = 0, r1 = 0;
  #pragma unroll 4
  for (int j = 0; j < 256; j++) {
    float a = Mb[j], bb = Mb[256 + j];
    r0 += (a > M0) || (a == M0 && j < tid);
    r1 += (bb > M1) || (bb == M1 && j < tid);
  }
  selv[tid] = meanx; selv[256 + tid] = meanx;
  if (r0 < 18) { int p = atomicAdd(&cnt, 1); items[p] = tid;       witem[p] = 0.25f * ac0; }
  if (r1 < 18) { int p = atomicAdd(&cnt, 1); items[p] = 256 + tid; witem[p] = 0.25f * ac1; }
  __syncthreads();
  int nIt = cnt;
  for (int i = w; i < nIt; i += 4) {
    int it = items[i]; float wv = witem[i];
    float m0 = (wv >= 0.f) ? wv * maxx : wv * minx;
    float S1 = 0.f, Sx = 0.f;
    #pragma unroll
    for (int cch = 0; cch < 4; cch++) {
      float xs = xr[lane + cch * 64];
      float e = __expf(fmaf(wv, xs, -m0));
      S1 += e; Sx = fmaf(xs, e, Sx);
    }
    #pragma unroll
    for (int m = 32; m > 0; m >>= 1) {
      S1 += __shfl_xor(S1, m); Sx += __shfl_xor(Sx, m);
    }
    if (lane == 0) selv[it] = Sx / S1;
  }
  __syncthreads();
  float2 gv; gv.x = selv[tid]; gv.y = selv[256 + tid];
  *(float2*)&g[(size_t)((seq << 8) + tid) * 8 + hg * 2] = gv;
}

// ---------------------------------------------------------------------------
// Mega-kernel: one block per (b, t-pair). 64 rows = 32 n x 2 t.
// LN1 -> x1s (bf16, LDS) -> GEMM1 (f-split across waves, w1 read once/block)
// -> relu -> a1s (half of f at a time) -> GEMM2 (per-wave full-c) -> LN2
// -> n-sum (shuffles + tiny LDS) -> out[b][c][t].
// MFMA 16x16x32 bf16: A[m=lane&15][k=quad*8+j], B[k=quad*8+j][n=lane&15],
// C/D: col=lane&15, row=quad*4+reg.
// ---------------------------------------------------------------------------
__global__ __launch_bounds__(256) void mega_kernel(
    const float* __restrict__ x, const float* __restrict__ g,
    const float* __restrict__ cst, const float* __restrict__ mlp_w,
    const unsigned short* __restrict__ w1bf, const float* __restrict__ b1,
    const unsigned short* __restrict__ w2bf, const float* __restrict__ b2,
    const float* __restrict__ ln1g, const float* __restrict__ ln1b,
    const float* __restrict__ ln2g, const float* __restrict__ ln2b,
    float* __restrict__ out) {
  __shared__ unsigned short x1s[64 * 136];   // rows stride 136 bf16 (16B-mult)
  __shared__ unsigned short a1s[64 * 264];   // half-f (256) + pad, stride 264
  __shared__ float partial[512];             // [wave][c]
  int tid = threadIdx.x, lane = tid & 63, w = tid >> 6;
  int col = lane & 15, quad = lane >> 4;
  int b = blockIdx.x >> 7, t0 = (blockIdx.x & 127) << 1;

  // ---- LN1: wave w handles rows w*16 .. w*16+15 (row = td*32 + n) ----
  {
    int c0 = lane << 1;
    float mwa = mlp_w[c0], mwb = mlp_w[c0 | 1];
    float cca = cst[1824 + c0], ccb = cst[1824 + (c0 | 1)];
    float wva[8], wvb[8];
    #pragma unroll
    for (int h = 0; h < 8; h++) {
      wva[h] = cst[800 + h * 128 + c0];
      wvb[h] = cst[800 + h * 128 + (c0 | 1)];
    }
    float g1a = ln1g[c0], g1b = ln1g[c0 | 1];
    float e1a = ln1b[c0], e1b = ln1b[c0 | 1];
    for (int tk = 0; tk < 16; tk++) {
      int row = w * 16 + tk;
      int td = row >> 5, n = row & 31;
      int tok = ((b * 32 + n) << 8) + t0 + td;
      float xvv = x[tok];
      const float* gp = g + (size_t)tok * 8;
      float ra = fmaf(xvv, mwa, cca), rb = fmaf(xvv, mwb, ccb);
      #pragma unroll
      for (int h = 0; h < 8; h++) {
        float gh = gp[h];
        ra = fmaf(gh, wva[h], ra); rb = fmaf(gh, wvb[h], rb);
      }
      float su = waveSum(ra + rb);
      float mu = su * (1.0f / 128.0f);
      float da = ra - mu, db = rb - mu;
      float vs = waveSum(da * da + db * db);
      float inv = rsqrtf(vs * (1.0f / 128.0f) + EPSF);
      unsigned int pa = f2bf(da * inv * g1a + e1a);
      unsigned int pb = f2bf(db * inv * g1b + e1b);
      *(unsigned int*)&x1s[row * 136 + c0] = pa | (pb << 16);
    }
  }
  __syncthreads();

  f32x4 acc2[8];
  #pragma unroll
  for (int i = 0; i < 8; i++) acc2[i] = (f32x4){0.f, 0.f, 0.f, 0.f};

  for (int fh = 0; fh < 2; fh++) {
    // ---- GEMM1: wave w covers ALL 64 rows x f-slice [fh*256+w*64, +64) ----
    f32x4 acc1[16];
    #pragma unroll
    for (int i = 0; i < 16; i++) acc1[i] = (f32x4){0.f, 0.f, 0.f, 0.f};
    #pragma unroll
    for (int ks = 0; ks < 4; ks++) {
      bf16x8 af[4];
      #pragma unroll
      for (int rg = 0; rg < 4; rg++)
        af[rg] = *(const bf16x8*)&x1s[(rg * 16 + col) * 136 + ks * 32 + quad * 8];
      #pragma unroll
      for (int ft = 0; ft < 4; ft++) {
        int f = fh * 256 + w * 64 + ft * 16 + col;
        bf16x8 bf = *(const bf16x8*)(w1bf + f * 128 + ks * 32 + quad * 8);
        #pragma unroll
        for (int rg = 0; rg < 4; rg++)
          acc1[rg * 4 + ft] = __builtin_amdgcn_mfma_f32_16x16x32_bf16(
              af[rg], bf, acc1[rg * 4 + ft], 0, 0, 0);
      }
    }
    if (fh) __syncthreads();   // previous half's a1s readers must finish
    // ---- relu + bias -> a1s ----
    #pragma unroll
    for (int ft = 0; ft < 4; ft++) {
      int fl = w * 64 + ft * 16 + col;
      float bv = b1[fh * 256 + fl];
      #pragma unroll
      for (int rg = 0; rg < 4; rg++) {
        f32x4 a = acc1[rg * 4 + ft];
        #pragma unroll
        for (int r = 0; r < 4; r++) {
          float vv = fmaxf(a[r] + bv, 0.f);
          a1s[(rg * 16 + quad * 4 + r) * 264 + fl] = f2bf(vv);
        }
      }
    }
    __syncthreads();
    // ---- GEMM2 half: wave w: rows w*16..+15, full c=128, K = this half ----
    #pragma unroll
    for (int ks = 0; ks < 8; ks++) {
      bf16x8 a2 = *(const bf16x8*)&a1s[(w * 16 + col) * 264 + ks * 32 + quad * 8];
      #pragma unroll
      for (int tc = 0; tc < 8; tc++) {
        int c = tc * 16 + col;
        bf16x8 bf = *(const bf16x8*)(w2bf + c * 512 + fh * 256 + ks * 32 + quad * 8);
        acc2[tc] = __builtin_amdgcn_mfma_f32_16x16x32_bf16(a2, bf, acc2[tc], 0, 0, 0);
      }
    }
  }

  // ---- epilogue: +b2, residual, LN2 (in-wave), n-sum, store ----
  float z[8][4];
  float b2c[8], g2c[8], e2c[8];
  #pragma unroll
  for (int tc = 0; tc < 8; tc++) {
    int c = tc * 16 + col;
    b2c[tc] = b2[c]; g2c[tc] = ln2g[c]; e2c[tc] = ln2b[c];
  }
  #pragma unroll
  for (int tc = 0; tc < 8; tc++)
    #pragma unroll
    for (int r = 0; r < 4; r++) {
      float x1v = bf2f(x1s[(w * 16 + quad * 4 + r) * 136 + tc * 16 + col]);
      z[tc][r] = acc2[tc][r] + b2c[tc] + x1v;
    }
  float mu[4], inv[4];
  #pragma unroll
  for (int r = 0; r < 4; r++) {
    float s = 0.f;
    #pragma unroll
    for (int tc = 0; tc < 8; tc++) s += z[tc][r];
    #pragma unroll
    for (int m = 1; m <= 8; m <<= 1) s += __shfl_xor(s, m);
    mu[r] = s * (1.0f / 128.0f);
  }
  #pragma unroll
  for (int r = 0; r < 4; r++) {
    float q = 0.f;
    #pragma unroll
    for (int tc = 0; tc < 8; tc++) {
      float d = z[tc][r] - mu[r]; q += d * d;
    }
    #pragma unroll
    for (int m = 1; m <= 8; m <<= 1) q += __shfl_xor(q, m);
    inv[r] = rsqrtf(q * (1.0f / 128.0f) + EPSF);
  }
  float nsum[8];
  #pragma unroll
  for (int tc = 0; tc < 8; tc++) {
    float s = 0.f;
    #pragma unroll
    for (int r = 0; r < 4; r++) {
      float o = (z[tc][r] - mu[r]) * inv[r] * g2c[tc] + e2c[tc];
      s += o;
    }
    s += __shfl_xor(s, 16);
    s += __shfl_xor(s, 32);
    nsum[tc] = s;
  }
  if (quad == 0) {
    #pragma unroll
    for (int tc = 0; tc < 8; tc++) partial[w * 128 + tc * 16 + col] = nsum[tc];
  }
  __syncthreads();
  {
    int c = tid & 127, tp = tid >> 7;
    float v = partial[(tp * 2) * 128 + c] + partial[(tp * 2 + 1) * 128 + c];
    out[(size_t)(b * 128 + c) * 256 + t0 + tp] = v;
  }
}

// ---------------------------------------------------------------------------
extern "C" void kernel_launch(void* const* d_in, const int* in_sizes, int n_in,
                              void* d_out, int out_size, void* d_ws, size_t ws_size,
                              hipStream_t stream) {
  (void)in_sizes; (void)n_in; (void)out_size; (void)ws_size;
  const float* x    = (const float*)d_in[0];
  const float* mlpw = (const float*)d_in[1];
  const float* mlpb = (const float*)d_in[2];
  const float* wq   = (const float*)d_in[3];
  const float* bq   = (const float*)d_in[4];
  const float* wk   = (const float*)d_in[5];
  const float* bk   = (const float*)d_in[6];
  const float* wv   = (const float*)d_in[7];
  const float* bv   = (const float*)d_in[8];
  const float* wo   = (const float*)d_in[9];
  const float* bo   = (const float*)d_in[10];
  const float* w1   = (const float*)d_in[11];
  const float* b1   = (const float*)d_in[12];
  const float* w2   = (const float*)d_in[13];
  const float* b2   = (const float*)d_in[14];
  const float* ln1g = (const float*)d_in[15];
  const float* ln1b = (const float*)d_in[16];
  const float* ln2g = (const float*)d_in[17];
  const float* ln2b = (const float*)d_in[18];

  char* ws = (char*)d_ws;
  int*            idxT = (int*)(ws);                       // 18,432 B
  float*          cst  = (float*)(ws + 20480);             //  7,808 B
  unsigned short* w1bf = (unsigned short*)(ws + 32768);    // 131,072 B
  unsigned short* w2bf = (unsigned short*)(ws + 163840);   // 131,072 B
  float*          gbuf = (float*)(ws + 294912);            // 1 MB
  float*          outp = (float*)d_out;

  hipLaunchKernelGGL(setup_kernel, dim3(32), dim3(256), 0, stream,
                     mlpw, mlpb, wq, bq, wk, bk, wv, bv, wo, bo, w1, w2,
                     idxT, cst, w1bf, w2bf);
  hipLaunchKernelGGL(attn_kernel, dim3(512), dim3(256), 0, stream,
                     x, idxT, cst, gbuf);
  hipLaunchKernelGGL(mega_kernel, dim3(512), dim3(256), 0, stream,
                     x, gbuf, cst, mlpw, w1bf, b1, w2bf, b2,
                     ln1g, ln1b, ln2g, ln2b, outp);
}

// Round 3
// 163.697 us; speedup vs baseline: 3.2368x; 1.0902x over previous
//
#include <hip/hip_runtime.h>
#include <stdint.h>
#include <math.h>

// InformerLayer on MI355X — round 3.
// h[t,c] = x_t*mlp_w[c] + mlp_b[c]  => attention collapses to scalar math on x;
// FFN is the only real GEMM -> bf16 MFMA (16x16x32), fused mega-kernel.
// Round-3: mega split to 1024 blocks (4/CU) with c-split GEMM2 (w2 read once
// per block); attn rank-count vectorized + half-wave softmax groups.

#define EPSF 1e-5f

typedef short bf16x8 __attribute__((ext_vector_type(8)));
typedef float f32x4  __attribute__((ext_vector_type(4)));

__device__ __forceinline__ unsigned short f2bf(float f) {
  union { float f; unsigned u; } v; v.f = f;
  unsigned r = v.u + 0x7FFFu + ((v.u >> 16) & 1u);
  return (unsigned short)(r >> 16);
}
__device__ __forceinline__ float bf2f(unsigned short u) {
  union { unsigned u; float f; } v; v.u = ((unsigned)u) << 16;
  return v.f;
}
__device__ __forceinline__ float waveSum(float v) {
  #pragma unroll
  for (int m = 32; m > 0; m >>= 1) v += __shfl_xor(v, m);
  return v;
}

// ---------------------------------------------------------------------------
// threefry2x32 with key (0, 42) == jax.random.key(42)
// ---------------------------------------------------------------------------
__device__ __forceinline__ void threefry2x32_k42(uint32_t& x0, uint32_t& x1) {
  const uint32_t ks0 = 0u, ks1 = 42u, ks2 = 0u ^ 42u ^ 0x1BD11BDAu;
  x0 += ks0; x1 += ks1;
#define TF_R(d) { x0 += x1; x1 = (x1 << d) | (x1 >> (32 - d)); x1 ^= x0; }
  TF_R(13) TF_R(15) TF_R(26) TF_R(6)  x0 += ks1; x1 += ks2 + 1u;
  TF_R(17) TF_R(29) TF_R(16) TF_R(24) x0 += ks2; x1 += ks0 + 2u;
  TF_R(13) TF_R(15) TF_R(26) TF_R(6)  x0 += ks0; x1 += ks1 + 3u;
  TF_R(17) TF_R(29) TF_R(16) TF_R(24) x0 += ks1; x1 += ks2 + 4u;
  TF_R(13) TF_R(15) TF_R(26) TF_R(6)  x0 += ks2; x1 += ks0 + 5u;
#undef TF_R
}

// ---------------------------------------------------------------------------
// Kernel A (grid 32): block 0: idxT + folded constants; all blocks: w -> bf16.
// cst layout (floats): 0 Aq[128] |128 cq |256 Ak |384 ck |512 Av |640 cv |
//   768 alpha[8] |776 beta[8] |784 gamma[8] |792 delta[8] |
//   800 Wv[8][128] |1824 ccol[128]
// ---------------------------------------------------------------------------
__global__ __launch_bounds__(256) void setup_kernel(
    const float* __restrict__ mlp_w, const float* __restrict__ mlp_b,
    const float* __restrict__ wq, const float* __restrict__ bq,
    const float* __restrict__ wk, const float* __restrict__ bk,
    const float* __restrict__ wv, const float* __restrict__ bv,
    const float* __restrict__ wo, const float* __restrict__ bo,
    const float* __restrict__ w1, const float* __restrict__ w2,
    int* __restrict__ idxT, float* __restrict__ cst,
    unsigned short* __restrict__ w1bf, unsigned short* __restrict__ w2bf) {
  int tid = threadIdx.x;
  {
    int gid = blockIdx.x * 256 + tid;        // 0..8191, 16 elems each
    int base = gid * 16;
    const float* src; unsigned short* dst; int off;
    if (base < 65536) { src = w1; dst = w1bf; off = base; }
    else              { src = w2; dst = w2bf; off = base - 65536; }
    #pragma unroll 4
    for (int k = 0; k < 16; k++) dst[off + k] = f2bf(src[off + k]);
  }
  if (blockIdx.x != 0) return;
  for (int p = tid; p < 2304; p += 256) {
    uint32_t a = (uint32_t)p, bb = (uint32_t)(p + 2304);
    threefry2x32_k42(a, bb);
    int l0 = p / 18, j0 = p - l0 * 18;
    int p2 = p + 2304;
    int l1 = p2 / 18, j1 = p2 - l1 * 18;
    idxT[j0 * 256 + l0] = (int)(a & 0xFFu);
    idxT[j1 * 256 + l1] = (int)(bb & 0xFFu);
  }
  if (tid < 128) {
    float aq = 0.f, cq_ = 0.f, ak = 0.f, ck_ = 0.f, av = 0.f, cv_ = 0.f;
    for (int c = 0; c < 128; c++) {
      float w = mlp_w[c], bb = mlp_b[c];
      float q = wq[tid * 128 + c], k = wk[tid * 128 + c], v = wv[tid * 128 + c];
      aq += q * w; cq_ += q * bb;
      ak += k * w; ck_ += k * bb;
      av += v * w; cv_ += v * bb;
    }
    cst[0   + tid] = aq;
    cst[128 + tid] = cq_ + bq[tid];
    cst[256 + tid] = ak;
    cst[384 + tid] = ck_ + bk[tid];
    cst[512 + tid] = av;
    cst[640 + tid] = cv_ + bv[tid];
  }
  __syncthreads();
  if (tid < 8) {
    float a = 0.f, b = 0.f, g = 0.f, d = 0.f;
    for (int e = 0; e < 16; e++) {
      int j = tid * 16 + e;
      float Aq = cst[j], Cq = cst[128 + j], Ak = cst[256 + j], Ck = cst[384 + j];
      a += Aq * Ak; b += Aq * Ck; g += Cq * Ak; d += Cq * Ck;
    }
    cst[768 + tid] = a; cst[776 + tid] = b; cst[784 + tid] = g; cst[792 + tid] = d;
  }
  if (tid < 128) {
    float oc = 0.f;
    for (int h = 0; h < 8; h++) {
      float s = 0.f;
      for (int e = 0; e < 16; e++) {
        float w = wo[tid * 128 + h * 16 + e];
        s  += w * cst[512 + h * 16 + e];   // Av
        oc += w * cst[640 + h * 16 + e];   // cv
      }
      cst[800 + h * 128 + tid] = s;        // Wv[h][i]
    }
    cst[1824 + tid] = oc + bo[tid] + mlp_b[tid];  // ccol
  }
}

// ---------------------------------------------------------------------------
// Kernel B: per (seq, head-pair). score(l,s) = a*x_l*x_s + b*x_l + g*x_s + d.
// Top-18 via vectorized rank counting; softmax rows on half-wave groups.
// ---------------------------------------------------------------------------
__global__ __launch_bounds__(256) void attn_kernel(
    const float* __restrict__ x, const int* __restrict__ idxT,
    const float* __restrict__ cst, float* __restrict__ g) {
  __shared__ float xr[256];
  __shared__ float Mb[512];     // [hl][l]
  __shared__ float selv[512];   // [hl][l]
  __shared__ float rsum[4], rmax[4], rmin[4];
  __shared__ int   items[64];
  __shared__ float witem[64];
  __shared__ int   cnt;
  int tid = threadIdx.x, lane = tid & 63, w = tid >> 6;
  int seq = blockIdx.x >> 2, hg = blockIdx.x & 3;
  if (tid == 0) cnt = 0;
  float xv = x[seq * 256 + tid];
  xr[tid] = xv;
  float s = waveSum(xv);
  float mx = xv, mn = xv;
  #pragma unroll
  for (int m = 32; m > 0; m >>= 1) {
    mx = fmaxf(mx, __shfl_xor(mx, m));
    mn = fminf(mn, __shfl_xor(mn, m));
  }
  if (lane == 0) { rsum[w] = s; rmax[w] = mx; rmin[w] = mn; }
  __syncthreads();
  float meanx = (rsum[0] + rsum[1] + rsum[2] + rsum[3]) * (1.0f / 256.0f);
  float maxx = fmaxf(fmaxf(rmax[0], rmax[1]), fmaxf(rmax[2], rmax[3]));
  float minx = fminf(fminf(rmin[0], rmin[1]), fminf(rmin[2], rmin[3]));
  // per-lane x chunk for the softmax phase (32-lane groups, 8 values each)
  int l32 = tid & 31, grp = tid >> 5;
  float xs8[8];
  #pragma unroll
  for (int k = 0; k < 8; k++) xs8[k] = xr[l32 + k * 32];
  // head-independent sample stats for query l = tid
  float mx18 = -INFINITY, mn18 = INFINITY, s18 = 0.f;
  #pragma unroll 3
  for (int j = 0; j < 18; j++) {
    float xs = xr[idxT[j * 256 + tid]];
    mx18 = fmaxf(mx18, xs); mn18 = fminf(mn18, xs); s18 += xs;
  }
  int h0 = hg * 2, h1 = h0 + 1;
  float al0 = cst[768 + h0], be0 = cst[776 + h0], ga0 = cst[784 + h0], de0 = cst[792 + h0];
  float al1 = cst[768 + h1], be1 = cst[776 + h1], ga1 = cst[784 + h1], de1 = cst[792 + h1];
  float ac0 = fmaf(al0, xv, ga0), cc0 = fmaf(be0, xv, de0);
  float ac1 = fmaf(al1, xv, ga1), cc1 = fmaf(be1, xv, de1);
  float M0 = ((ac0 >= 0.f ? ac0 * mx18 : ac0 * mn18) + cc0)
           - (fmaf(ac0, s18, 18.f * cc0)) * (1.0f / 256.0f);
  float M1 = ((ac1 >= 0.f ? ac1 * mx18 : ac1 * mn18) + cc1)
           - (fmaf(ac1, s18, 18.f * cc1)) * (1.0f / 256.0f);
  Mb[tid] = M0; Mb[256 + tid] = M1;
  __syncthreads();
  // vectorized rank counting (tie-break: smaller index wins, matches top_k)
  int r0 = 0, r1 = 0;
  const float4* Mb4 = (const float4*)Mb;
  #pragma unroll 4
  for (int j4 = 0; j4 < 64; j4++) {
    float4 a = Mb4[j4], bb = Mb4[64 + j4];
    int base = j4 * 4;
    r0 += (a.x > M0) || (a.x == M0 && base     < tid);
    r0 += (a.y > M0) || (a.y == M0 && base + 1 < tid);
    r0 += (a.z > M0) || (a.z == M0 && base + 2 < tid);
    r0 += (a.w > M0) || (a.w == M0 && base + 3 < tid);
    r1 += (bb.x > M1) || (bb.x == M1 && base     < tid);
    r1 += (bb.y > M1) || (bb.y == M1 && base + 1 < tid);
    r1 += (bb.z > M1) || (bb.z == M1 && base + 2 < tid);
    r1 += (bb.w > M1) || (bb.w == M1 && base + 3 < tid);
  }
  selv[tid] = meanx; selv[256 + tid] = meanx;
  if (r0 < 18) { int p = atomicAdd(&cnt, 1); items[p] = tid;       witem[p] = 0.25f * ac0; }
  if (r1 < 18) { int p = atomicAdd(&cnt, 1); items[p] = 256 + tid; witem[p] = 0.25f * ac1; }
  __syncthreads();
  int nIt = cnt;
  for (int i = grp; i < nIt; i += 8) {
    int it = items[i]; float wv = witem[i];
    float m0 = (wv >= 0.f) ? wv * maxx : wv * minx;
    float S1 = 0.f, Sx = 0.f;
    #pragma unroll
    for (int k = 0; k < 8; k++) {
      float e = __expf(fmaf(wv, xs8[k], -m0));
      S1 += e; Sx = fmaf(xs8[k], e, Sx);
    }
    #pragma unroll
    for (int m = 16; m > 0; m >>= 1) {
      S1 += __shfl_xor(S1, m); Sx += __shfl_xor(Sx, m);
    }
    if (l32 == 0) selv[it] = Sx / S1;
  }
  __syncthreads();
  float2 gv; gv.x = selv[tid]; gv.y = selv[256 + tid];
  *(float2*)&g[(size_t)((seq << 8) + tid) * 8 + hg * 2] = gv;
}

// ---------------------------------------------------------------------------
// Mega-kernel: one block per (b, t). 32 rows = the N dim (summed at the end).
// LN1 -> x1s(bf16) -> GEMM1 (f-split/wave, w1 once per block) -> relu -> a1s
// (half f at a time) -> GEMM2 (c-split/wave, w2 once per block) -> zbuf(f32)
// -> LN2 + n-sum (shuffles) -> out[b][c][t].
// MFMA 16x16x32 bf16: A[m=lane&15][k=quad*8+j], B[k=quad*8+j][n=lane&15],
// C/D: col=lane&15, row=quad*4+reg.
// ---------------------------------------------------------------------------
__global__ __launch_bounds__(256, 4) void mega_kernel(
    const float* __restrict__ x, const float* __restrict__ g,
    const float* __restrict__ cst, const float* __restrict__ mlp_w,
    const unsigned short* __restrict__ w1bf, const float* __restrict__ b1,
    const unsigned short* __restrict__ w2bf, const float* __restrict__ b2,
    const float* __restrict__ ln1g, const float* __restrict__ ln1b,
    const float* __restrict__ ln2g, const float* __restrict__ ln2b,
    float* __restrict__ out) {
  __shared__ unsigned short x1s[32 * 136];   // 8704 B, row stride 272 B
  __shared__ char ovl[32 * 264 * 2];         // a1s (bf16) / zbuf (f32) overlay
  __shared__ float psum[512];                // [wave][c]
  unsigned short* a1s = (unsigned short*)ovl;    // stride 264 bf16
  float*          zbuf = (float*)ovl;            // stride 132 f32
  int tid = threadIdx.x, lane = tid & 63, w = tid >> 6;
  int col = lane & 15, quad = lane >> 4;
  int b = blockIdx.x >> 8, t = blockIdx.x & 255;

  // ---- LN1: wave w handles rows (n) w*8 .. w*8+7 ----
  {
    int c0 = lane << 1;
    float mwa = mlp_w[c0], mwb = mlp_w[c0 | 1];
    float cca = cst[1824 + c0], ccb = cst[1824 + (c0 | 1)];
    float wva[8], wvb[8];
    #pragma unroll
    for (int h = 0; h < 8; h++) {
      wva[h] = cst[800 + h * 128 + c0];
      wvb[h] = cst[800 + h * 128 + (c0 | 1)];
    }
    float g1a = ln1g[c0], g1b = ln1g[c0 | 1];
    float e1a = ln1b[c0], e1b = ln1b[c0 | 1];
    for (int tk = 0; tk < 8; tk++) {
      int n = w * 8 + tk;
      int tok = ((b * 32 + n) << 8) + t;
      float xvv = x[tok];
      float4 gA = *(const float4*)(g + (size_t)tok * 8);
      float4 gB = *(const float4*)(g + (size_t)tok * 8 + 4);
      float ra = fmaf(xvv, mwa, cca), rb = fmaf(xvv, mwb, ccb);
      ra = fmaf(gA.x, wva[0], ra); rb = fmaf(gA.x, wvb[0], rb);
      ra = fmaf(gA.y, wva[1], ra); rb = fmaf(gA.y, wvb[1], rb);
      ra = fmaf(gA.z, wva[2], ra); rb = fmaf(gA.z, wvb[2], rb);
      ra = fmaf(gA.w, wva[3], ra); rb = fmaf(gA.w, wvb[3], rb);
      ra = fmaf(gB.x, wva[4], ra); rb = fmaf(gB.x, wvb[4], rb);
      ra = fmaf(gB.y, wva[5], ra); rb = fmaf(gB.y, wvb[5], rb);
      ra = fmaf(gB.z, wva[6], ra); rb = fmaf(gB.z, wvb[6], rb);
      ra = fmaf(gB.w, wva[7], ra); rb = fmaf(gB.w, wvb[7], rb);
      float su = waveSum(ra + rb);
      float mu = su * (1.0f / 128.0f);
      float da = ra - mu, db = rb - mu;
      float vs = waveSum(da * da + db * db);
      float inv = rsqrtf(vs * (1.0f / 128.0f) + EPSF);
      unsigned int pa = f2bf(da * inv * g1a + e1a);
      unsigned int pb = f2bf(db * inv * g1b + e1b);
      *(unsigned int*)&x1s[n * 136 + c0] = pa | (pb << 16);
    }
  }
  __syncthreads();

  f32x4 acc2[4];   // [rg][tc]
  #pragma unroll
  for (int i = 0; i < 4; i++) acc2[i] = (f32x4){0.f, 0.f, 0.f, 0.f};

  for (int fh = 0; fh < 2; fh++) {
    // ---- GEMM1: all 32 rows x f-slice [fh*256 + w*64, +64) ----
    f32x4 acc1[8];   // [rg][ft]
    #pragma unroll
    for (int i = 0; i < 8; i++) acc1[i] = (f32x4){0.f, 0.f, 0.f, 0.f};
    #pragma unroll
    for (int ks = 0; ks < 4; ks++) {
      bf16x8 af[2];
      #pragma unroll
      for (int rg = 0; rg < 2; rg++)
        af[rg] = *(const bf16x8*)&x1s[(rg * 16 + col) * 136 + ks * 32 + quad * 8];
      #pragma unroll
      for (int ft = 0; ft < 4; ft++) {
        int f = fh * 256 + w * 64 + ft * 16 + col;
        bf16x8 bfr = *(const bf16x8*)(w1bf + f * 128 + ks * 32 + quad * 8);
        #pragma unroll
        for (int rg = 0; rg < 2; rg++)
          acc1[rg * 4 + ft] = __builtin_amdgcn_mfma_f32_16x16x32_bf16(
              af[rg], bfr, acc1[rg * 4 + ft], 0, 0, 0);
      }
    }
    if (fh) __syncthreads();   // previous half's a1s readers must finish
    // ---- relu + bias -> a1s ----
    #pragma unroll
    for (int ft = 0; ft < 4; ft++) {
      int fl = w * 64 + ft * 16 + col;
      float bv = b1[fh * 256 + fl];
      #pragma unroll
      for (int rg = 0; rg < 2; rg++) {
        f32x4 a = acc1[rg * 4 + ft];
        #pragma unroll
        for (int r = 0; r < 4; r++) {
          float vv = fmaxf(a[r] + bv, 0.f);
          a1s[(rg * 16 + quad * 4 + r) * 264 + fl] = f2bf(vv);
        }
      }
    }
    __syncthreads();
    // ---- GEMM2 half: c-slice [w*32, +32), all rows, K = this half ----
    #pragma unroll
    for (int ks = 0; ks < 8; ks++) {
      bf16x8 a2[2];
      #pragma unroll
      for (int rg = 0; rg < 2; rg++)
        a2[rg] = *(const bf16x8*)&a1s[(rg * 16 + col) * 264 + ks * 32 + quad * 8];
      #pragma unroll
      for (int tc = 0; tc < 2; tc++) {
        int c = w * 32 + tc * 16 + col;
        bf16x8 bfr = *(const bf16x8*)(w2bf + c * 512 + fh * 256 + ks * 32 + quad * 8);
        #pragma unroll
        for (int rg = 0; rg < 2; rg++)
          acc2[rg * 2 + tc] = __builtin_amdgcn_mfma_f32_16x16x32_bf16(
              a2[rg], bfr, acc2[rg * 2 + tc], 0, 0, 0);
      }
    }
  }
  __syncthreads();   // all a1s readers done before zbuf overwrite

  // ---- +b2 + residual -> zbuf (f32, stride 132) ----
  #pragma unroll
  for (int tc = 0; tc < 2; tc++) {
    int c = w * 32 + tc * 16 + col;
    float b2c = b2[c];
    #pragma unroll
    for (int rg = 0; rg < 2; rg++) {
      #pragma unroll
      for (int r = 0; r < 4; r++) {
        int row = rg * 16 + quad * 4 + r;
        float z = acc2[rg * 2 + tc][r] + b2c + bf2f(x1s[row * 136 + c]);
        zbuf[row * 132 + c] = z;
      }
    }
  }
  __syncthreads();

  // ---- LN2 + n-sum: wave w rows w*8..+7; lane = (rloc, part) ----
  {
    int rloc = lane & 7, part = lane >> 3;
    int row = w * 8 + rloc;
    float4 zv[4];
    #pragma unroll
    for (int q = 0; q < 4; q++)
      zv[q] = *(const float4*)&zbuf[row * 132 + part * 16 + q * 4];
    float s = 0.f;
    #pragma unroll
    for (int q = 0; q < 4; q++) s += zv[q].x + zv[q].y + zv[q].z + zv[q].w;
    s += __shfl_xor(s, 8); s += __shfl_xor(s, 16); s += __shfl_xor(s, 32);
    float mu = s * (1.0f / 128.0f);
    float ss = 0.f;
    #pragma unroll
    for (int q = 0; q < 4; q++) {
      float d0 = zv[q].x - mu, d1 = zv[q].y - mu, d2 = zv[q].z - mu, d3 = zv[q].w - mu;
      ss += d0 * d0 + d1 * d1 + d2 * d2 + d3 * d3;
    }
    ss += __shfl_xor(ss, 8); ss += __shfl_xor(ss, 16); ss += __shfl_xor(ss, 32);
    float inv = rsqrtf(ss * (1.0f / 128.0f) + EPSF);
    float4 o[4];
    #pragma unroll
    for (int q = 0; q < 4; q++) {
      float4 g2v = *(const float4*)(ln2g + part * 16 + q * 4);
      float4 e2v = *(const float4*)(ln2b + part * 16 + q * 4);
      o[q].x = (zv[q].x - mu) * inv * g2v.x + e2v.x;
      o[q].y = (zv[q].y - mu) * inv * g2v.y + e2v.y;
      o[q].z = (zv[q].z - mu) * inv * g2v.z + e2v.z;
      o[q].w = (zv[q].w - mu) * inv * g2v.w + e2v.w;
    }
    // sum over this wave's 8 rows (xor over rloc bits 1,2,4)
    #pragma unroll
    for (int m = 1; m <= 4; m <<= 1) {
      #pragma unroll
      for (int q = 0; q < 4; q++) {
        o[q].x += __shfl_xor(o[q].x, m);
        o[q].y += __shfl_xor(o[q].y, m);
        o[q].z += __shfl_xor(o[q].z, m);
        o[q].w += __shfl_xor(o[q].w, m);
      }
    }
    if (rloc == 0) {
      #pragma unroll
      for (int q = 0; q < 4; q++)
        *(float4*)&psum[w * 128 + part * 16 + q * 4] = o[q];
    }
  }
  __syncthreads();
  if (tid < 128) {
    int c = tid;
    float v = psum[c] + psum[128 + c] + psum[256 + c] + psum[384 + c];
    out[(size_t)(b * 128 + c) * 256 + t] = v;
  }
}

// ---------------------------------------------------------------------------
extern "C" void kernel_launch(void* const* d_in, const int* in_sizes, int n_in,
                              void* d_out, int out_size, void* d_ws, size_t ws_size,
                              hipStream_t stream) {
  (void)in_sizes; (void)n_in; (void)out_size; (void)ws_size;
  const float* x    = (const float*)d_in[0];
  const float* mlpw = (const float*)d_in[1];
  const float* mlpb = (const float*)d_in[2];
  const float* wq   = (const float*)d_in[3];
  const float* bq   = (const float*)d_in[4];
  const float* wk   = (const float*)d_in[5];
  const float* bk   = (const float*)d_in[6];
  const float* wv   = (const float*)d_in[7];
  const float* bv   = (const float*)d_in[8];
  const float* wo   = (const float*)d_in[9];
  const float* bo   = (const float*)d_in[10];
  const float* w1   = (const float*)d_in[11];
  const float* b1   = (const float*)d_in[12];
  const float* w2   = (const float*)d_in[13];
  const float* b2   = (const float*)d_in[14];
  const float* ln1g = (const float*)d_in[15];
  const float* ln1b = (const float*)d_in[16];
  const float* ln2g = (const float*)d_in[17];
  const float* ln2b = (const float*)d_in[18];

  char* ws = (char*)d_ws;
  int*            idxT = (int*)(ws);                       // 18,432 B
  float*          cst  = (float*)(ws + 20480);             //  7,808 B
  unsigned short* w1bf = (unsigned short*)(ws + 32768);    // 131,072 B
  unsigned short* w2bf = (unsigned short*)(ws + 163840);   // 131,072 B
  float*          gbuf = (float*)(ws + 294912);            // 1 MB
  float*          outp = (float*)d_out;

  hipLaunchKernelGGL(setup_kernel, dim3(32), dim3(256), 0, stream,
                     mlpw, mlpb, wq, bq, wk, bk, wv, bv, wo, bo, w1, w2,
                     idxT, cst, w1bf, w2bf);
  hipLaunchKernelGGL(attn_kernel, dim3(512), dim3(256), 0, stream,
                     x, idxT, cst, gbuf);
  hipLaunchKernelGGL(mega_kernel, dim3(1024), dim3(256), 0, stream,
                     x, gbuf, cst, mlpw, w1bf, b1, w2bf, b2,
                     ln1g, ln1b, ln2g, ln2b, outp);
}